// Round 3
// baseline (464.273 us; speedup 1.0000x reference)
//
#include <hip/hip_runtime.h>
#include <hip/hip_bf16.h>
#include <stdint.h>

// MoE: E=8 experts, M=4096 tokens, K=2048 hidden, I=1408 intermediate, TOPK=2
#define EXPERTS 8
#define MTOK 4096
#define KDIM 2048
#define IDIM 1408
#define NDIM 2816   // 2*I
#define CAP  8192   // per-expert bucket capacity (worst case)

typedef __attribute__((ext_vector_type(8))) short bf16x8;
typedef __attribute__((ext_vector_type(4))) float f32x4;

__device__ __forceinline__ unsigned short f2bf(float x) {
    unsigned u = __float_as_uint(x);
    u = u + 0x7fffu + ((u >> 16) & 1u);   // RNE
    return (unsigned short)(u >> 16);
}

__device__ __forceinline__ void gload16(const void* g, void* l) {
    __builtin_amdgcn_global_load_lds(
        (const __attribute__((address_space(1))) void*)g,
        (__attribute__((address_space(3))) void*)l, 16, 0, 0);
}

// ---------------- fp32 -> bf16 conversion (vectorized) ----------------
__global__ void __launch_bounds__(256) conv_bf16(const float* __restrict__ src,
                                                 unsigned short* __restrict__ dst, int n4) {
    int i = blockIdx.x * 256 + threadIdx.x;
    int st = gridDim.x * 256;
    for (; i < n4; i += st) {
        float4 v = reinterpret_cast<const float4*>(src)[i];
        ushort4 r;
        r.x = f2bf(v.x); r.y = f2bf(v.y); r.z = f2bf(v.z); r.w = f2bf(v.w);
        reinterpret_cast<ushort4*>(dst)[i] = r;
    }
}

// ---------------- router ----------------
__global__ void __launch_bounds__(256) router(const float* __restrict__ tw,
                                              const int* __restrict__ ids,
                                              int* __restrict__ tok, float* __restrict__ wgt,
                                              int* __restrict__ cnt) {
    int m = blockIdx.x * 256 + threadIdx.x;
    if (m >= MTOK) return;
#pragma unroll
    for (int t = 0; t < 2; t++) {
        int e = ids[m * 2 + t];
        int slot = atomicAdd(&cnt[e], 1);
        tok[e * CAP + slot] = m;
        wgt[e * CAP + slot] = tw[m * 2 + t];
    }
}

__global__ void scan_off(const int* __restrict__ cnt, int* __restrict__ off) {
    if (threadIdx.x == 0) {
        int s = 0;
        for (int e = 0; e < EXPERTS; e++) { off[e] = s; s += cnt[e]; }
    }
}

// ====================================================================
// GEMM1: 128x256 tile, BK=64, 8 waves (2Mx4N), 3-tile LDS ring (144KB),
// 4 phases per K-tile, counted vmcnt(6), setprio around MFMA clusters.
// LDS slot (48KB): A[128 rows][128B] at +0, B[256 rows][128B] at +16384.
// Swizzle: 16B slot g_phys = g_log ^ (row & 7) (2-way bank alias = free);
// staged via inverse-permuted global source, read with same XOR.
// ====================================================================
__global__ void __launch_bounds__(512, 2) gemm1_silu(
    const unsigned short* __restrict__ hsb,
    const unsigned short* __restrict__ w1b,
    const int* __restrict__ tok,
    const int* __restrict__ cnt,
    const int* __restrict__ off,
    unsigned short* __restrict__ act) {
    const int cb = blockIdx.x;   // 0..10 (11 * 128 = 1408 I-cols, gate+up interleaved)
    const int rb = blockIdx.y;   // row-block of 128
    const int e  = blockIdx.z;
    const int cnt_e = cnt[e];
    if (rb * 128 >= cnt_e) return;
    const int off_e = off[e];
    const int NT = KDIM / 64;    // 32

    __shared__ __align__(16) char smem[147456];   // 3 x 48KB ring
    __shared__ int toks[128];

    const int tid = threadIdx.x;
    const int lane = tid & 63;
    const int w = tid >> 6;
    if (tid < 128) {
        int slot = rb * 128 + tid;
        toks[tid] = (slot < cnt_e) ? tok[e * CAP + slot] : 0;
    }
    __syncthreads();

    // ---- staging sources: 6 x 16B chunks per thread (A:2, B:4), linear LDS dest
    size_t sA[2]; int dA[2];
#pragma unroll
    for (int c = 0; c < 2; c++) {
        int i = c * 512 + tid;
        int row = i >> 3, gp = i & 7, gl = gp ^ (row & 7);
        sA[c] = (size_t)toks[row] * KDIM + gl * 8;
        dA[c] = i * 16;
    }
    size_t sB[4]; int dB[4];
    const size_t w1base = (size_t)e * (size_t)NDIM * KDIM;
#pragma unroll
    for (int c = 0; c < 4; c++) {
        int j = c * 512 + tid;
        int row = j >> 3, gp = j & 7, gl = gp ^ (row & 7);
        int G = row >> 4;   // 0..15; even = gate row, odd = up row (same 16-col slice)
        int w1row = ((G & 1) ? IDIM : 0) + cb * 128 + (G >> 1) * 16 + (row & 15);
        sB[c] = w1base + (size_t)w1row * KDIM + gl * 8;
        dB[c] = 16384 + j * 16;
    }

    // ---- reader fragment offsets
    const int wr = w >> 2, wc = w & 3;   // 2M x 4N wave grid, wave tile 64x64
    const int l16 = lane & 15, lg = lane >> 4;
    int aoff[4][2], boff[4][2];
#pragma unroll
    for (int m = 0; m < 4; m++) {
        int row = wr * 64 + m * 16 + l16;
#pragma unroll
        for (int h = 0; h < 2; h++)
            aoff[m][h] = row * 128 + (((h * 4 + lg) ^ (row & 7)) * 16);
    }
#pragma unroll
    for (int n = 0; n < 4; n++) {
        int row = wc * 64 + n * 16 + l16;
#pragma unroll
        for (int h = 0; h < 2; h++)
            boff[n][h] = 16384 + row * 128 + (((h * 4 + lg) ^ (row & 7)) * 16);
    }

    f32x4 acc[4][4];
#pragma unroll
    for (int m = 0; m < 4; m++)
#pragma unroll
        for (int n = 0; n < 4; n++) acc[m][n] = {0.f, 0.f, 0.f, 0.f};

#define STG_A(t, base) { const int ko_ = (t) * 64; \
    gload16(hsb + sA[0] + ko_, (base) + dA[0]); \
    gload16(hsb + sA[1] + ko_, (base) + dA[1]); }
#define STG_B01(t, base) { const int ko_ = (t) * 64; \
    gload16(w1b + sB[0] + ko_, (base) + dB[0]); \
    gload16(w1b + sB[1] + ko_, (base) + dB[1]); }
#define STG_B23(t, base) { const int ko_ = (t) * 64; \
    gload16(w1b + sB[2] + ko_, (base) + dB[2]); \
    gload16(w1b + sB[3] + ko_, (base) + dB[3]); }

    // prologue: stage tiles 0 and 1; wait tile 0 (6 of 12 outstanding)
    STG_A(0, smem); STG_B01(0, smem); STG_B23(0, smem);
    { char* s1 = smem + 49152; STG_A(1, s1); STG_B01(1, s1); STG_B23(1, s1); }
    asm volatile("s_waitcnt vmcnt(6)" ::: "memory");
    __builtin_amdgcn_sched_barrier(0);
    __builtin_amdgcn_s_barrier();

    int cb_o = 0;        // ring byte offset of tile t
    int st_o = 98304;    // ring byte offset of tile t+2

#pragma unroll 1
    for (int t = 0; t < NT; ++t) {
        char* db = smem + cb_o;
        char* sb = smem + st_o;
        const bool stg = (t + 2 < NT);
        const int ko = (t + 2) * 64;

        // ---------- P0: read all B frags + A[0]; stage A
        bf16x8 bv0[4], bv1[4];
#pragma unroll
        for (int n = 0; n < 4; n++) {
            bv0[n] = *(const bf16x8*)(db + boff[n][0]);
            bv1[n] = *(const bf16x8*)(db + boff[n][1]);
        }
        bf16x8 a0 = *(const bf16x8*)(db + aoff[0][0]);
        bf16x8 a1 = *(const bf16x8*)(db + aoff[0][1]);
        if (stg) { gload16(hsb + sA[0] + ko, sb + dA[0]); gload16(hsb + sA[1] + ko, sb + dA[1]); }
        __builtin_amdgcn_sched_barrier(0);
        __builtin_amdgcn_s_barrier();
        asm volatile("s_waitcnt lgkmcnt(0)" ::: "memory");
        __builtin_amdgcn_sched_barrier(0);
        __builtin_amdgcn_s_setprio(1);
#pragma unroll
        for (int n = 0; n < 4; n++) acc[0][n] = __builtin_amdgcn_mfma_f32_16x16x32_bf16(a0, bv0[n], acc[0][n], 0, 0, 0);
#pragma unroll
        for (int n = 0; n < 4; n++) acc[0][n] = __builtin_amdgcn_mfma_f32_16x16x32_bf16(a1, bv1[n], acc[0][n], 0, 0, 0);
        __builtin_amdgcn_s_setprio(0);
        __builtin_amdgcn_sched_barrier(0);

        // ---------- P1: A[1]; stage B01
        a0 = *(const bf16x8*)(db + aoff[1][0]);
        a1 = *(const bf16x8*)(db + aoff[1][1]);
        if (stg) { gload16(w1b + sB[0] + ko, sb + dB[0]); gload16(w1b + sB[1] + ko, sb + dB[1]); }
        __builtin_amdgcn_sched_barrier(0);
        __builtin_amdgcn_s_barrier();
        asm volatile("s_waitcnt lgkmcnt(0)" ::: "memory");
        __builtin_amdgcn_sched_barrier(0);
        __builtin_amdgcn_s_setprio(1);
#pragma unroll
        for (int n = 0; n < 4; n++) acc[1][n] = __builtin_amdgcn_mfma_f32_16x16x32_bf16(a0, bv0[n], acc[1][n], 0, 0, 0);
#pragma unroll
        for (int n = 0; n < 4; n++) acc[1][n] = __builtin_amdgcn_mfma_f32_16x16x32_bf16(a1, bv1[n], acc[1][n], 0, 0, 0);
        __builtin_amdgcn_s_setprio(0);
        __builtin_amdgcn_sched_barrier(0);

        // ---------- P2: A[2]; stage B23
        a0 = *(const bf16x8*)(db + aoff[2][0]);
        a1 = *(const bf16x8*)(db + aoff[2][1]);
        if (stg) { gload16(w1b + sB[2] + ko, sb + dB[2]); gload16(w1b + sB[3] + ko, sb + dB[3]); }
        __builtin_amdgcn_sched_barrier(0);
        __builtin_amdgcn_s_barrier();
        asm volatile("s_waitcnt lgkmcnt(0)" ::: "memory");
        __builtin_amdgcn_sched_barrier(0);
        __builtin_amdgcn_s_setprio(1);
#pragma unroll
        for (int n = 0; n < 4; n++) acc[2][n] = __builtin_amdgcn_mfma_f32_16x16x32_bf16(a0, bv0[n], acc[2][n], 0, 0, 0);
#pragma unroll
        for (int n = 0; n < 4; n++) acc[2][n] = __builtin_amdgcn_mfma_f32_16x16x32_bf16(a1, bv1[n], acc[2][n], 0, 0, 0);
        __builtin_amdgcn_s_setprio(0);
        __builtin_amdgcn_sched_barrier(0);

        // ---------- P3: A[3]; no stage; counted vmcnt + ring barrier
        a0 = *(const bf16x8*)(db + aoff[3][0]);
        a1 = *(const bf16x8*)(db + aoff[3][1]);
        __builtin_amdgcn_sched_barrier(0);
        __builtin_amdgcn_s_barrier();
        asm volatile("s_waitcnt lgkmcnt(0)" ::: "memory");
        __builtin_amdgcn_sched_barrier(0);
        __builtin_amdgcn_s_setprio(1);
#pragma unroll
        for (int n = 0; n < 4; n++) acc[3][n] = __builtin_amdgcn_mfma_f32_16x16x32_bf16(a0, bv0[n], acc[3][n], 0, 0, 0);
#pragma unroll
        for (int n = 0; n < 4; n++) acc[3][n] = __builtin_amdgcn_mfma_f32_16x16x32_bf16(a1, bv1[n], acc[3][n], 0, 0, 0);
        __builtin_amdgcn_s_setprio(0);
        __builtin_amdgcn_sched_barrier(0);
        if (t + 2 < NT)      { asm volatile("s_waitcnt vmcnt(6)" ::: "memory"); }
        else if (t + 1 < NT) { asm volatile("s_waitcnt vmcnt(0)" ::: "memory"); }
        __builtin_amdgcn_sched_barrier(0);
        __builtin_amdgcn_s_barrier();

        cb_o += 49152; if (cb_o == 147456) cb_o = 0;
        st_o += 49152; if (st_o == 147456) st_o = 0;
    }
#undef STG_A
#undef STG_B01
#undef STG_B23

    // epilogue: within wave, n pairs (0,1),(2,3) are (gate,up) on same 16 cols
#pragma unroll
    for (int m = 0; m < 4; m++) {
#pragma unroll
        for (int p = 0; p < 2; p++) {
            f32x4 g4 = acc[m][p * 2];
            f32x4 u4 = acc[m][p * 2 + 1];
            int icol = cb * 128 + (wc * 2 + p) * 16 + l16;
#pragma unroll
            for (int j = 0; j < 4; j++) {
                int grow = rb * 128 + wr * 64 + m * 16 + lg * 4 + j;
                if (grow < cnt_e) {
                    float gt = g4[j], up = u4[j];
                    float s = gt / (1.f + __expf(-gt));
                    act[(size_t)(off_e + grow) * IDIM + icol] = f2bf(s * up);
                }
            }
        }
    }
}

// ---------------- GEMM2 + weighted scatter (round-1 known-good) ----------------
__global__ void __launch_bounds__(256) gemm2_scatter(
    const unsigned short* __restrict__ act,
    const unsigned short* __restrict__ w2b,
    const int* __restrict__ tok,
    const float* __restrict__ wgt,
    const int* __restrict__ cnt,
    const int* __restrict__ off,
    float* __restrict__ out) {
    const int cb = blockIdx.x;   // 0..15 (16*128 = 2048 out cols)
    const int rb = blockIdx.y;
    const int e  = blockIdx.z;
    const int cnt_e = cnt[e];
    if (rb * 128 >= cnt_e) return;
    const int off_e = off[e];

    __shared__ unsigned short As[128 * 32];
    __shared__ unsigned short Bs[128 * 32];
    __shared__ int toks[128];
    __shared__ float wgts[128];

    const int tid = threadIdx.x;
    const int w = tid >> 6, lane = tid & 63;
    if (tid < 128) {
        int slot = rb * 128 + tid;
        bool v = slot < cnt_e;
        toks[tid] = v ? tok[e * CAP + slot] : 0;
        wgts[tid] = v ? wgt[e * CAP + slot] : 0.f;
    }
    __syncthreads();

    const int o0 = w * 1024 + lane * 16;
    const int row0 = o0 >> 6, g0 = ((o0 >> 4) & 3) ^ ((row0 >> 1) & 3);
    const int o1 = 4096 + o0;
    const int row1 = o1 >> 6, g1 = ((o1 >> 4) & 3) ^ ((row1 >> 1) & 3);

    const int s0 = rb * 128 + row0, s1 = rb * 128 + row1;
    const size_t pa0 = (size_t)(off_e + (s0 < cnt_e ? s0 : 0)) * IDIM + g0 * 8;
    const size_t pa1 = (size_t)(off_e + (s1 < cnt_e ? s1 : 0)) * IDIM + g1 * 8;
    const size_t w2base = (size_t)e * KDIM * IDIM;
    const size_t pb0 = w2base + (size_t)(cb * 128 + row0) * IDIM + g0 * 8;
    const size_t pb1 = w2base + (size_t)(cb * 128 + row1) * IDIM + g1 * 8;

    const int wr = w >> 1, wc = w & 1;
    const int l16 = lane & 15, lg = lane >> 4;

    f32x4 acc[4][4];
#pragma unroll
    for (int m = 0; m < 4; m++)
#pragma unroll
        for (int n = 0; n < 4; n++) acc[m][n] = {0.f, 0.f, 0.f, 0.f};

    char* Ab = (char*)As;
    char* Bb = (char*)Bs;

    for (int kt = 0; kt < IDIM / 32; ++kt) {
        const int kof = kt * 32;
        gload16(act + pa0 + kof, Ab + w * 1024);
        gload16(act + pa1 + kof, Ab + 4096 + w * 1024);
        gload16(w2b + pb0 + kof, Bb + w * 1024);
        gload16(w2b + pb1 + kof, Bb + 4096 + w * 1024);
        __syncthreads();

        bf16x8 a[4], b[4];
#pragma unroll
        for (int m = 0; m < 4; m++) {
            int r = wr * 64 + m * 16 + l16;
            a[m] = *reinterpret_cast<bf16x8*>(Ab + r * 64 + ((lg ^ ((r >> 1) & 3)) * 16));
        }
#pragma unroll
        for (int n = 0; n < 4; n++) {
            int r = wc * 64 + n * 16 + l16;
            b[n] = *reinterpret_cast<bf16x8*>(Bb + r * 64 + ((lg ^ ((r >> 1) & 3)) * 16));
        }
#pragma unroll
        for (int m = 0; m < 4; m++)
#pragma unroll
            for (int n = 0; n < 4; n++)
                acc[m][n] = __builtin_amdgcn_mfma_f32_16x16x32_bf16(a[m], b[n], acc[m][n], 0, 0, 0);
        __syncthreads();
    }

    // scatter: out[token, k] += weight * y  (TOPK=2, fp32 atomic add, commutative)
#pragma unroll
    for (int m = 0; m < 4; m++) {
#pragma unroll
        for (int n = 0; n < 4; n++) {
            int kcol = cb * 128 + wc * 64 + n * 16 + l16;
#pragma unroll
            for (int j = 0; j < 4; j++) {
                int lrow = wr * 64 + m * 16 + lg * 4 + j;
                if (rb * 128 + lrow < cnt_e) {
                    atomicAdd(&out[(size_t)toks[lrow] * KDIM + kcol],
                              wgts[lrow] * acc[m][n][j]);
                }
            }
        }
    }
}

extern "C" void kernel_launch(void* const* d_in, const int* in_sizes, int n_in,
                              void* d_out, int out_size, void* d_ws, size_t ws_size,
                              hipStream_t stream) {
    const float* hs  = (const float*)d_in[0];
    const float* w1  = (const float*)d_in[1];
    const float* w2  = (const float*)d_in[2];
    const float* tw  = (const float*)d_in[3];
    const int*   ids = (const int*)d_in[4];
    float* out = (float*)d_out;

    char* ws = (char*)d_ws;
    unsigned short* w1b  = (unsigned short*)(ws);                  //  92,274,688
    unsigned short* w2b  = (unsigned short*)(ws + 92274688ull);    //  46,137,344
    unsigned short* hsb  = (unsigned short*)(ws + 138412032ull);   //  16,777,216
    unsigned short* actb = (unsigned short*)(ws + 155189248ull);   //  23,068,672
    int*   tokb = (int*)  (ws + 178257920ull);
    float* wgtb = (float*)(ws + 178520064ull);
    int*   cntb = (int*)  (ws + 178782208ull);
    int*   offb = (int*)  (ws + 178782240ull);

    hipMemsetAsync(d_out, 0, (size_t)MTOK * KDIM * sizeof(float), stream);
    hipMemsetAsync(cntb, 0, 64, stream);

    conv_bf16<<<4096, 256, 0, stream>>>(w1, w1b, EXPERTS * NDIM * KDIM / 4);
    conv_bf16<<<2048, 256, 0, stream>>>(w2, w2b, EXPERTS * KDIM * IDIM / 4);
    conv_bf16<<<1024, 256, 0, stream>>>(hs, hsb, MTOK * KDIM / 4);

    router<<<MTOK / 256, 256, 0, stream>>>(tw, ids, tokb, wgtb, cntb);
    scan_off<<<1, 64, 0, stream>>>(cntb, offb);

    gemm1_silu<<<dim3(11, 64, 8), 512, 0, stream>>>(hsb, w1b, tokb, cntb, offb, actb);
    gemm2_scatter<<<dim3(16, 64, 8), 256, 0, stream>>>(actb, w2b, tokb, wgtb, cntb, offb, out);
}

// Round 4
// 383.297 us; speedup vs baseline: 1.2113x; 1.2113x over previous
//
#include <hip/hip_runtime.h>
#include <hip/hip_bf16.h>
#include <stdint.h>

// MoE: E=8 experts, M=4096 tokens, K=2048 hidden, I=1408 intermediate, TOPK=2
#define EXPERTS 8
#define MTOK 4096
#define KDIM 2048
#define IDIM 1408
#define NDIM 2816   // 2*I
#define CAP  8192   // per-expert bucket capacity (worst case)

typedef __attribute__((ext_vector_type(8))) short bf16x8;
typedef __attribute__((ext_vector_type(4))) float f32x4;

__device__ __forceinline__ unsigned short f2bf(float x) {
    unsigned u = __float_as_uint(x);
    u = u + 0x7fffu + ((u >> 16) & 1u);   // RNE
    return (unsigned short)(u >> 16);
}

__device__ __forceinline__ void gload16(const void* g, void* l) {
    __builtin_amdgcn_global_load_lds(
        (const __attribute__((address_space(1))) void*)g,
        (__attribute__((address_space(3))) void*)l, 16, 0, 0);
}

// ---------------- fp32 -> bf16 conversion (vectorized) ----------------
__global__ void __launch_bounds__(256) conv_bf16(const float* __restrict__ src,
                                                 unsigned short* __restrict__ dst, int n4) {
    int i = blockIdx.x * 256 + threadIdx.x;
    int st = gridDim.x * 256;
    for (; i < n4; i += st) {
        float4 v = reinterpret_cast<const float4*>(src)[i];
        ushort4 r;
        r.x = f2bf(v.x); r.y = f2bf(v.y); r.z = f2bf(v.z); r.w = f2bf(v.w);
        reinterpret_cast<ushort4*>(dst)[i] = r;
    }
}

// ---------------- router ----------------
__global__ void __launch_bounds__(256) router(const float* __restrict__ tw,
                                              const int* __restrict__ ids,
                                              int* __restrict__ tok, float* __restrict__ wgt,
                                              int* __restrict__ cnt) {
    int m = blockIdx.x * 256 + threadIdx.x;
    if (m >= MTOK) return;
#pragma unroll
    for (int t = 0; t < 2; t++) {
        int e = ids[m * 2 + t];
        int slot = atomicAdd(&cnt[e], 1);
        tok[e * CAP + slot] = m;
        wgt[e * CAP + slot] = tw[m * 2 + t];
    }
}

__global__ void scan_off(const int* __restrict__ cnt, int* __restrict__ off) {
    if (threadIdx.x == 0) {
        int s = 0;
        for (int e = 0; e < EXPERTS; e++) { off[e] = s; s += cnt[e]; }
    }
}

// ====================================================================
// Round-1 known-good 128x128 GEMMs + expert->XCD pinning:
// linear grid, bid = j*8 + e  =>  XCD(bid%8) == e, so each XCD's L2
// only ever holds ONE expert's weight panels.
// ====================================================================

// ---------------- GEMM1 + SiLU*up -> act (bf16) ----------------
__global__ void __launch_bounds__(256) gemm1_silu(
    const unsigned short* __restrict__ hsb,
    const unsigned short* __restrict__ w1b,
    const int* __restrict__ tok,
    const int* __restrict__ cnt,
    const int* __restrict__ off,
    unsigned short* __restrict__ act) {
    const int bid = blockIdx.x;
    const int e = bid & 7;       // XCD pin: bid%8 -> XCD
    const int j = bid >> 3;      // 0..1407
    const int rb = j / 22;       // rb-major: co-resident blocks share A rows
    const int cb = j - rb * 22;  // 0..21 (22*64 = 1408 gate cols)
    const int cnt_e = cnt[e];
    if (rb * 128 >= cnt_e) return;
    const int off_e = off[e];

    __shared__ unsigned short As[128 * 32];  // 8KB [row][64B], swizzled slots
    __shared__ unsigned short Bs[128 * 32];
    __shared__ int toks[128];

    const int tid = threadIdx.x;
    const int w = tid >> 6, lane = tid & 63;
    if (tid < 128) {
        int slot = rb * 128 + tid;
        toks[tid] = (slot < cnt_e) ? tok[e * CAP + slot] : 0;
    }
    __syncthreads();

    // staging geometry: two 16B chunks per thread; linear LDS dest,
    // source k-group pre-swizzled: g = s ^ ((row>>1)&3)
    const int o0 = w * 1024 + lane * 16;
    const int row0 = o0 >> 6, g0 = ((o0 >> 4) & 3) ^ ((row0 >> 1) & 3);
    const int o1 = 4096 + o0;
    const int row1 = o1 >> 6, g1 = ((o1 >> 4) & 3) ^ ((row1 >> 1) & 3);

    const int G0 = row0 >> 4, G1 = row1 >> 4;
    const size_t w1base = (size_t)e * NDIM * KDIM;
    const int wrow0 = ((G0 & 1) ? IDIM : 0) + cb * 64 + (G0 >> 1) * 16 + (row0 & 15);
    const int wrow1 = ((G1 & 1) ? IDIM : 0) + cb * 64 + (G1 >> 1) * 16 + (row1 & 15);

    const int wr = w >> 1, wc = w & 1;
    const int l16 = lane & 15, lg = lane >> 4;

    f32x4 acc[4][4];
#pragma unroll
    for (int m = 0; m < 4; m++)
#pragma unroll
        for (int n = 0; n < 4; n++) acc[m][n] = {0.f, 0.f, 0.f, 0.f};

    char* Ab = (char*)As;
    char* Bb = (char*)Bs;
    const size_t srcA0 = (size_t)toks[row0] * KDIM + g0 * 8;
    const size_t srcA1 = (size_t)toks[row1] * KDIM + g1 * 8;
    const size_t srcB0 = w1base + (size_t)wrow0 * KDIM + g0 * 8;
    const size_t srcB1 = w1base + (size_t)wrow1 * KDIM + g1 * 8;

    for (int kt = 0; kt < KDIM / 32; ++kt) {
        const int kof = kt * 32;
        gload16(hsb + srcA0 + kof, Ab + w * 1024);
        gload16(hsb + srcA1 + kof, Ab + 4096 + w * 1024);
        gload16(w1b + srcB0 + kof, Bb + w * 1024);
        gload16(w1b + srcB1 + kof, Bb + 4096 + w * 1024);
        __syncthreads();

        bf16x8 a[4], b[4];
#pragma unroll
        for (int m = 0; m < 4; m++) {
            int r = wr * 64 + m * 16 + l16;
            a[m] = *reinterpret_cast<bf16x8*>(Ab + r * 64 + ((lg ^ ((r >> 1) & 3)) * 16));
        }
#pragma unroll
        for (int n = 0; n < 4; n++) {
            int r = wc * 64 + n * 16 + l16;
            b[n] = *reinterpret_cast<bf16x8*>(Bb + r * 64 + ((lg ^ ((r >> 1) & 3)) * 16));
        }
#pragma unroll
        for (int m = 0; m < 4; m++)
#pragma unroll
            for (int n = 0; n < 4; n++)
                acc[m][n] = __builtin_amdgcn_mfma_f32_16x16x32_bf16(a[m], b[n], acc[m][n], 0, 0, 0);
        __syncthreads();
    }

    // epilogue: n even = gate frag, n+1 = up frag (same 16 cols)
#pragma unroll
    for (int m = 0; m < 4; m++) {
#pragma unroll
        for (int np = 0; np < 2; np++) {
            f32x4 g4 = acc[m][np * 2];
            f32x4 u4 = acc[m][np * 2 + 1];
            int icol = cb * 64 + (wc * 2 + np) * 16 + l16;
#pragma unroll
            for (int j2 = 0; j2 < 4; j2++) {
                int grow = rb * 128 + wr * 64 + m * 16 + lg * 4 + j2;
                if (grow < cnt_e) {
                    float gt = g4[j2], up = u4[j2];
                    float s = gt / (1.f + __expf(-gt));
                    act[(size_t)(off_e + grow) * IDIM + icol] = f2bf(s * up);
                }
            }
        }
    }
}

// ---------------- GEMM2 + weighted scatter ----------------
__global__ void __launch_bounds__(256) gemm2_scatter(
    const unsigned short* __restrict__ act,
    const unsigned short* __restrict__ w2b,
    const int* __restrict__ tok,
    const float* __restrict__ wgt,
    const int* __restrict__ cnt,
    const int* __restrict__ off,
    float* __restrict__ out) {
    const int bid = blockIdx.x;
    const int e = bid & 7;       // XCD pin, same expert->XCD map as gemm1
    const int j = bid >> 3;      // 0..1023
    const int rb = j >> 4;       // rb-major
    const int cb = j & 15;       // 0..15 (16*128 = 2048 out cols)
    const int cnt_e = cnt[e];
    if (rb * 128 >= cnt_e) return;
    const int off_e = off[e];

    __shared__ unsigned short As[128 * 32];
    __shared__ unsigned short Bs[128 * 32];
    __shared__ int toks[128];
    __shared__ float wgts[128];

    const int tid = threadIdx.x;
    const int w = tid >> 6, lane = tid & 63;
    if (tid < 128) {
        int slot = rb * 128 + tid;
        bool v = slot < cnt_e;
        toks[tid] = v ? tok[e * CAP + slot] : 0;
        wgts[tid] = v ? wgt[e * CAP + slot] : 0.f;
    }
    __syncthreads();

    const int o0 = w * 1024 + lane * 16;
    const int row0 = o0 >> 6, g0 = ((o0 >> 4) & 3) ^ ((row0 >> 1) & 3);
    const int o1 = 4096 + o0;
    const int row1 = o1 >> 6, g1 = ((o1 >> 4) & 3) ^ ((row1 >> 1) & 3);

    const int s0 = rb * 128 + row0, s1 = rb * 128 + row1;
    const size_t pa0 = (size_t)(off_e + (s0 < cnt_e ? s0 : 0)) * IDIM + g0 * 8;
    const size_t pa1 = (size_t)(off_e + (s1 < cnt_e ? s1 : 0)) * IDIM + g1 * 8;
    const size_t w2base = (size_t)e * KDIM * IDIM;
    const size_t pb0 = w2base + (size_t)(cb * 128 + row0) * IDIM + g0 * 8;
    const size_t pb1 = w2base + (size_t)(cb * 128 + row1) * IDIM + g1 * 8;

    const int wr = w >> 1, wc = w & 1;
    const int l16 = lane & 15, lg = lane >> 4;

    f32x4 acc[4][4];
#pragma unroll
    for (int m = 0; m < 4; m++)
#pragma unroll
        for (int n = 0; n < 4; n++) acc[m][n] = {0.f, 0.f, 0.f, 0.f};

    char* Ab = (char*)As;
    char* Bb = (char*)Bs;

    for (int kt = 0; kt < IDIM / 32; ++kt) {
        const int kof = kt * 32;
        gload16(act + pa0 + kof, Ab + w * 1024);
        gload16(act + pa1 + kof, Ab + 4096 + w * 1024);
        gload16(w2b + pb0 + kof, Bb + w * 1024);
        gload16(w2b + pb1 + kof, Bb + 4096 + w * 1024);
        __syncthreads();

        bf16x8 a[4], b[4];
#pragma unroll
        for (int m = 0; m < 4; m++) {
            int r = wr * 64 + m * 16 + l16;
            a[m] = *reinterpret_cast<bf16x8*>(Ab + r * 64 + ((lg ^ ((r >> 1) & 3)) * 16));
        }
#pragma unroll
        for (int n = 0; n < 4; n++) {
            int r = wc * 64 + n * 16 + l16;
            b[n] = *reinterpret_cast<bf16x8*>(Bb + r * 64 + ((lg ^ ((r >> 1) & 3)) * 16));
        }
#pragma unroll
        for (int m = 0; m < 4; m++)
#pragma unroll
            for (int n = 0; n < 4; n++)
                acc[m][n] = __builtin_amdgcn_mfma_f32_16x16x32_bf16(a[m], b[n], acc[m][n], 0, 0, 0);
        __syncthreads();
    }

    // scatter: out[token, k] += weight * y  (TOPK=2, fp32 atomic add, commutative)
#pragma unroll
    for (int m = 0; m < 4; m++) {
#pragma unroll
        for (int n = 0; n < 4; n++) {
            int kcol = cb * 128 + wc * 64 + n * 16 + l16;
#pragma unroll
            for (int j2 = 0; j2 < 4; j2++) {
                int lrow = wr * 64 + m * 16 + lg * 4 + j2;
                if (rb * 128 + lrow < cnt_e) {
                    atomicAdd(&out[(size_t)toks[lrow] * KDIM + kcol],
                              wgts[lrow] * acc[m][n][j2]);
                }
            }
        }
    }
}

extern "C" void kernel_launch(void* const* d_in, const int* in_sizes, int n_in,
                              void* d_out, int out_size, void* d_ws, size_t ws_size,
                              hipStream_t stream) {
    const float* hs  = (const float*)d_in[0];
    const float* w1  = (const float*)d_in[1];
    const float* w2  = (const float*)d_in[2];
    const float* tw  = (const float*)d_in[3];
    const int*   ids = (const int*)d_in[4];
    float* out = (float*)d_out;

    char* ws = (char*)d_ws;
    unsigned short* w1b  = (unsigned short*)(ws);                  //  92,274,688
    unsigned short* w2b  = (unsigned short*)(ws + 92274688ull);    //  46,137,344
    unsigned short* hsb  = (unsigned short*)(ws + 138412032ull);   //  16,777,216
    unsigned short* actb = (unsigned short*)(ws + 155189248ull);   //  23,068,672
    int*   tokb = (int*)  (ws + 178257920ull);
    float* wgtb = (float*)(ws + 178520064ull);
    int*   cntb = (int*)  (ws + 178782208ull);
    int*   offb = (int*)  (ws + 178782240ull);

    hipMemsetAsync(d_out, 0, (size_t)MTOK * KDIM * sizeof(float), stream);
    hipMemsetAsync(cntb, 0, 64, stream);

    conv_bf16<<<4096, 256, 0, stream>>>(w1, w1b, EXPERTS * NDIM * KDIM / 4);
    conv_bf16<<<2048, 256, 0, stream>>>(w2, w2b, EXPERTS * KDIM * IDIM / 4);
    conv_bf16<<<1024, 256, 0, stream>>>(hs, hsb, MTOK * KDIM / 4);

    router<<<MTOK / 256, 256, 0, stream>>>(tw, ids, tokb, wgtb, cntb);
    scan_off<<<1, 64, 0, stream>>>(cntb, offb);

    // linear grids with bid%8 == expert  (expert->XCD pinning)
    gemm1_silu<<<dim3(22 * 64 * 8, 1, 1), 256, 0, stream>>>(hsb, w1b, tokb, cntb, offb, actb);
    gemm2_scatter<<<dim3(16 * 64 * 8, 1, 1), 256, 0, stream>>>(actb, w2b, tokb, wgtb, cntb, offb, out);
}